// Round 14
// baseline (3783.698 us; speedup 1.0000x reference)
//
#include <hip/hip_runtime.h>
#include <cstdint>
#include <cstddef>

#define CIN 512
#define NA 36864           // 4096 positions * 9 anchors
#define NPRE 6000
#define NPOST 300
#define NWORD 94           // ceil(6000/64)
#define NEGV -1000000000.0f
#define ISTRIDE 76         // input LDS row stride (19 quads, odd -> bank spread)

// d_out float offsets (return-order concat)
#define O_LOCS   0
#define O_SCORES 1179648   // 8*36864*4
#define O_ROIS   1769472   // + 8*36864*2
#define O_RIDX   1779072   // + 8*300*4
#define O_ANCH   1781472   // + 8*300

// ---------- exact-rounding helpers (ordering-critical code only) --------------------
__device__ __forceinline__ float fmulr(float a, float b) { return __fmul_rn(a, b); }
__device__ __forceinline__ float faddr(float a, float b) { return __fadd_rn(a, b); }
__device__ __forceinline__ float fsubr(float a, float b) { return __fsub_rn(a, b); }

__device__ __forceinline__ void anchor_for(int a, int pos, float* anc) {
    const double rat[3] = {0.5, 1.0, 2.0};
    const double scl[3] = {8.0, 16.0, 32.0};
    int ri = a / 3, si = a - ri * 3;
    double h = 16.0 * scl[si] * sqrt(rat[ri]);
    double w = 16.0 * scl[si] * sqrt(1.0 / rat[ri]);
    float a0 = (float)(8.0 - h * 0.5);
    float a1 = (float)(8.0 - w * 0.5);
    float a2 = (float)(8.0 + h * 0.5);
    float a3 = (float)(8.0 + w * 0.5);
    int y = pos >> 6, x = pos & 63;
    float sy = (float)(y * 16), sx = (float)(x * 16);
    anc[0] = faddr(a0, sy); anc[1] = faddr(a1, sx);
    anc[2] = faddr(a2, sy); anc[3] = faddr(a3, sx);
}

__device__ __forceinline__ bool decode_box(float4 L, const float* anc, float* box) {
    float ah  = fsubr(anc[2], anc[0]);
    float aw  = fsubr(anc[3], anc[1]);
    float acy = faddr(anc[0], fmulr(0.5f, ah));
    float acx = faddr(anc[1], fmulr(0.5f, aw));
    float cy  = faddr(fmulr(L.x, ah), acy);
    float cx  = faddr(fmulr(L.y, aw), acx);
    float h   = fmulr(ah, expf(L.z));
    float w   = fmulr(aw, expf(L.w));
    float y1 = fminf(fmaxf(fsubr(cy, fmulr(0.5f, h)), 0.0f), 1024.0f);
    float x1 = fminf(fmaxf(fsubr(cx, fmulr(0.5f, w)), 0.0f), 1024.0f);
    float y2 = fminf(fmaxf(faddr(cy, fmulr(0.5f, h)), 0.0f), 1024.0f);
    float x2 = fminf(fmaxf(faddr(cx, fmulr(0.5f, w)), 0.0f), 1024.0f);
    box[0] = y1; box[1] = x1; box[2] = y2; box[3] = x2;
    float hs = fsubr(y2, y1), ws2 = fsubr(x2, x1);
    return (hs >= 16.0f) && (ws2 >= 16.0f);
}

// monotonic 64-bit map of a double (totally ordered, sign handled)
__device__ __forceinline__ unsigned long long mono64(double f) {
    unsigned long long u = (unsigned long long)__double_as_longlong(f);
    return (u & 0x8000000000000000ull) ? ~u : (u | 0x8000000000000000ull);
}

// ---------------- weight reorder: w1[oc][c][ky][kx] -> wr2[ocb64][ct(c*9+tap)][o64] --
__global__ __launch_bounds__(256) void k_wreord(const float* __restrict__ w1,
                                                float* __restrict__ wr2) {
    __shared__ float tile[64][37];
    const int ct0 = blockIdx.x * 36;   // 128 chunks over 4608
    const int ocb = blockIdx.y;        // 8
    const int t = threadIdx.x;
    for (int i = t; i < 64 * 36; i += 256) {
        int orow = i / 36, c = i - orow * 36;
        tile[orow][c] = w1[(size_t)(ocb * 64 + orow) * 4608 + ct0 + c];
    }
    __syncthreads();
    for (int i = t; i < 36 * 64; i += 256) {
        int ct = i >> 6, o = i & 63;
        wr2[((size_t)ocb * 4608 + ct0 + ct) * 64 + o] = tile[o][ct];
    }
}

// ---------------- 3x3 conv 512->512 + bias + relu, pure fp32 -------------------------
// Per-thread 4 oc x 2 rows x 8 cols; ROLLING 2-row input window (live rows 48->~30
// floats) + launch_bounds(256,3) -> target 3 waves/SIMD. Per-output tap sequence
// (cc -> dy -> dx, o/rr/j inner, 8-ch fp32 sub merged to fp32 acc) IDENTICAL to
// rounds 5-13 -> bit-identical mid. Spill tripwire: WRITE_SIZE must stay ~65MB.
__global__ __launch_bounds__(256, 3) void k_conv3(const float* __restrict__ x,
                                                  const float* __restrict__ wr2,
                                                  const float* __restrict__ b1,
                                                  float* __restrict__ mid) {
    __shared__ float in_s[8 * 6 * ISTRIDE];   // 3648 floats
    __shared__ float w_s[8 * 9 * 64];         // 4608 floats
    const int yb  = blockIdx.x;          // 16
    const int ocb = blockIdx.y;          // 8
    const int n   = blockIdx.z;          // 8
    const int t   = threadIdx.x;
    const int y0  = yb * 4;
    const int cg  = t & 7;               // col group: cols cg*8..cg*8+7
    const int rg  = (t >> 3) & 1;        // row pair: rows rg*2, rg*2+1
    const int ocg = t >> 4;              // 0..15 -> ocs ocg*4..ocg*4+3
    const int xo  = cg << 3;

    // zero halo words (gx=-1 at word 4, gx=64 at word 69) on all 48 rows, once
    if (t < 48) { in_s[t * ISTRIDE + 4] = 0.f; in_s[t * ISTRIDE + 69] = 0.f; }

    // staging: 768 f4 slots (48 rows x 16), 3 per thread; dest word 5+4c is 4B-aligned
    int   ilds[3];
    int   ival[3];
    const float* igp[3];
#pragma unroll
    for (int k = 0; k < 3; ++k) {
        int s = t + k * 256;
        int row = s >> 4, c = s & 15;
        int cc = row / 6, rr = row - cc * 6;
        int gy = y0 - 1 + rr;
        ival[k] = (gy >= 0 && gy < 64) ? 1 : 0;
        int gyc = min(max(gy, 0), 63);
        ilds[k] = row * ISTRIDE + 5 + c * 4;
        igp[k]  = x + (((size_t)(n * CIN + cc) * 64 + gyc) * 64 + c * 4);
    }
    const float* wgp = wr2 + (size_t)ocb * (4608 * 64);

    float acc[4][2][8];
#pragma unroll
    for (int o = 0; o < 4; o++)
#pragma unroll
        for (int rr = 0; rr < 2; rr++)
#pragma unroll
            for (int j = 0; j < 8; j++) acc[o][rr][j] = 0.f;

    for (int ch = 0; ch < 64; ++ch) {
        // ---- stage weights: linear float4 copy of 4608 floats ----
        const float* wp0 = wgp + (size_t)ch * 4608;
#pragma unroll
        for (int k = 0; k < 4; ++k)
            *(float4*)&w_s[4 * t + 1024 * k] = *(const float4*)(wp0 + 4 * t + 1024 * k);
        if (t < 128)
            *(float4*)&w_s[4 * t + 4096] = *(const float4*)(wp0 + 4 * t + 4096);
        // ---- stage input: 3 slots per thread (aligned global f4 -> 4 b32 LDS) ----
#pragma unroll
        for (int k = 0; k < 3; ++k) {
            float4 v = make_float4(0.f, 0.f, 0.f, 0.f);
            if (ival[k]) v = *(const float4*)(igp[k] + (size_t)ch * 32768);
            in_s[ilds[k] + 0] = v.x;
            in_s[ilds[k] + 1] = v.y;
            in_s[ilds[k] + 2] = v.z;
            in_s[ilds[k] + 3] = v.w;
        }
        __syncthreads();

        float sub[4][2][8];
#pragma unroll
        for (int o = 0; o < 4; o++)
#pragma unroll
            for (int rr = 0; rr < 2; rr++)
#pragma unroll
                for (int j = 0; j < 8; j++) sub[o][rr][j] = 0.f;
#pragma unroll 1
        for (int cc = 0; cc < 8; ++cc) {
            const float* rowbase = &in_s[cc * (6 * ISTRIDE) + xo + 4];
            float r0[12], r1[12], r2[12], r3[12];
#define LOADROW(dst, K)                                                        \
            {                                                                  \
                const float4* ip = (const float4*)(rowbase + (rg * 2 + (K)) * ISTRIDE); \
                float4 A = ip[0], B = ip[1], C4 = ip[2];                       \
                dst[0] = A.x;  dst[1] = A.y;  dst[2]  = A.z;  dst[3]  = A.w;   \
                dst[4] = B.x;  dst[5] = B.y;  dst[6]  = B.z;  dst[7]  = B.w;   \
                dst[8] = C4.x; dst[9] = C4.y; dst[10] = C4.z; dst[11] = C4.w;  \
            }
#define MACDY(DY, RA, RB)                                                      \
            {                                                                  \
                _Pragma("unroll")                                              \
                for (int dx = 0; dx < 3; ++dx) {                               \
                    const float4* wp =                                         \
                        (const float4*)&w_s[cc * 576 + ((DY) * 3 + dx) * 64 + ocg * 4]; \
                    float4 W = wp[0];                                          \
                    float w4[4] = {W.x, W.y, W.z, W.w};                        \
                    _Pragma("unroll")                                          \
                    for (int o = 0; o < 4; ++o) {                              \
                        _Pragma("unroll")                                      \
                        for (int j = 0; j < 8; ++j)                            \
                            sub[o][0][j] += w4[o] * RA[j + dx];                \
                        _Pragma("unroll")                                      \
                        for (int j = 0; j < 8; ++j)                            \
                            sub[o][1][j] += w4[o] * RB[j + dx];                \
                    }                                                          \
                }                                                              \
            }
            LOADROW(r0, 0)
            LOADROW(r1, 1)
            MACDY(0, r0, r1)
            LOADROW(r2, 2)
            MACDY(1, r1, r2)
            LOADROW(r3, 3)
            MACDY(2, r2, r3)
#undef LOADROW
#undef MACDY
        }
#pragma unroll
        for (int o = 0; o < 4; o++)
#pragma unroll
            for (int rr = 0; rr < 2; rr++)
#pragma unroll
                for (int j = 0; j < 8; j++) acc[o][rr][j] += sub[o][rr][j];
        __syncthreads();
    }
    const int ocbase = (ocb << 6) + ocg * 4;
#pragma unroll
    for (int o = 0; o < 4; o++) {
        float bb = b1[ocbase + o];
#pragma unroll
        for (int rr = 0; rr < 2; rr++) {
            const int gy = y0 + rg * 2 + rr;
            float4 v0, v1;
            v0.x = fmaxf(acc[o][rr][0] + bb, 0.f);
            v0.y = fmaxf(acc[o][rr][1] + bb, 0.f);
            v0.z = fmaxf(acc[o][rr][2] + bb, 0.f);
            v0.w = fmaxf(acc[o][rr][3] + bb, 0.f);
            v1.x = fmaxf(acc[o][rr][4] + bb, 0.f);
            v1.y = fmaxf(acc[o][rr][5] + bb, 0.f);
            v1.z = fmaxf(acc[o][rr][6] + bb, 0.f);
            v1.w = fmaxf(acc[o][rr][7] + bb, 0.f);
            float* mp = &mid[((size_t)(n * CIN + ocbase + o) * 64 + gy) * 64 + xo];
            *(float4*)(mp + 0) = v0;
            *(float4*)(mp + 4) = v1;
        }
    }
}

// ---------------- fused 1x1 convs (36 loc + 18 score), f64 accumulation --------------
__global__ __launch_bounds__(256) void k_conv1(const float* __restrict__ mid,
                                               const float* __restrict__ wl,
                                               const float* __restrict__ bl,
                                               const float* __restrict__ wsc,
                                               const float* __restrict__ bs,
                                               float* __restrict__ out,
                                               double* __restrict__ fgbuf) {
    __shared__ float in_s[128 * 64];
    __shared__ float w_s[128 * 64];   // [cc][og*16+k], invalid slots zero
    const int y = blockIdx.x;   // 64
    const int n = blockIdx.y;   // 8
    const int t = threadIdx.x;
    const int xx = t & 63, og = t >> 6;   // og uniform per wave
    double accd[14];
#pragma unroll
    for (int k = 0; k < 14; k++) accd[k] = 0.0;

    for (int c0 = 0; c0 < 512; c0 += 128) {
        for (int idx = t; idx < 128 * 64; idx += 256) {
            int cc = idx >> 6, x2 = idx & 63;
            in_s[idx] = mid[((n * CIN + c0 + cc) * 64 + y) * 64 + x2];
        }
        for (int idx = t; idx < 128 * 64; idx += 256) {
            int cc = idx >> 6, s = idx & 63;
            int og2 = s >> 4, kk = s & 15;
            int oc = og2 * 14 + kk;
            float v = 0.f;
            if (kk < 14 && oc < 54)
                v = (oc < 36) ? wl[oc * 512 + c0 + cc] : wsc[(oc - 36) * 512 + c0 + cc];
            w_s[cc * 64 + s] = v;
        }
        __syncthreads();
#pragma unroll 1
        for (int cc = 0; cc < 128; ++cc) {
            double iv = (double)in_s[cc * 64 + xx];
            const float4* wq = (const float4*)&w_s[cc * 64 + og * 16];
            float4 W0 = wq[0], W1 = wq[1], W2 = wq[2], W3 = wq[3];
            float wf[16] = {W0.x, W0.y, W0.z, W0.w, W1.x, W1.y, W1.z, W1.w,
                            W2.x, W2.y, W2.z, W2.w, W3.x, W3.y, W3.z, W3.w};
#pragma unroll
            for (int k = 0; k < 14; k++)
                accd[k] += (double)wf[k] * iv;
        }
        __syncthreads();
    }
    const int pos = y * 64 + xx;
    double sv[14];
#pragma unroll
    for (int k = 0; k < 14; k++) {
        int oc = og * 14 + k;
        if (oc >= 54) break;
        if (oc < 36) {
            double v = accd[k] + (double)bl[oc];
            int a = oc >> 2, cd = oc & 3;
            out[O_LOCS + ((size_t)(n * NA + pos * 9 + a)) * 4 + cd] = (float)v;
        } else {
            sv[k] = accd[k] + (double)bs[oc - 36];
            int c2 = oc - 36, a = c2 >> 1, cls = c2 & 1;
            out[O_SCORES + ((size_t)(n * NA + pos * 9 + a)) * 2 + cls] = (float)sv[k];
        }
    }
#pragma unroll
    for (int k = 0; k < 13; k++) {
        int oc = og * 14 + k;
        if (oc >= 36 && oc < 54 && ((oc - 36) & 1) == 0) {
            double s0 = sv[k], s1 = sv[k + 1];
            double m = fmax(s0, s1);
            double e0 = exp(s0 - m), e1 = exp(s1 - m);
            double fg = e1 / (e0 + e1);
            int a = (oc - 36) >> 1;
            fgbuf[(size_t)n * NA + pos * 9 + a] = fg;
        }
    }
}

// ---------------- keys: mono64(f64 fg) low 16 bits = inverted index; + anchors -------
__global__ __launch_bounds__(256) void k_keys(const float* __restrict__ out_ro,
                                              const double* __restrict__ fgbuf,
                                              unsigned long long* __restrict__ keys,
                                              float* __restrict__ out) {
    const int n = blockIdx.x / 144;
    const int i = (blockIdx.x % 144) * 256 + threadIdx.x;
    int pos = i / 9, a = i - pos * 9;
    float anc[4]; anchor_for(a, pos, anc);
    float4 L = *(const float4*)&out_ro[O_LOCS + (size_t)(n * NA + i) * 4];
    float box[4];
    bool ok = decode_box(L, anc, box);
    double f = ok ? fgbuf[(size_t)n * NA + i] : (double)NEGV;
    unsigned long long m = mono64(f);
    keys[(size_t)n * NA + i] =
        (m & 0xFFFFFFFFFFFF0000ull) | (unsigned long long)(0xFFFFu - (unsigned)i);
    if (blockIdx.x < 144) {   // n == 0: also emit anchors output
        out[O_ANCH + (size_t)i * 4 + 0] = anc[0];
        out[O_ANCH + (size_t)i * 4 + 1] = anc[1];
        out[O_ANCH + (size_t)i * 4 + 2] = anc[2];
        out[O_ANCH + (size_t)i * 4 + 3] = anc[3];
    }
}

// ---------------- fused top-6000: exact radix select + compact + rank-by-count -------
// One block per image, 1024 threads. LDS union: 34KB select phase / 48KB key array.
// Select: 5 levels (13+13+13+13+12), suffix-scan group pick. Compact exactly 6000
// keys >= kth into LDS; rank = #{keys > mine} (broadcast reads); decode + scatter.
__global__ __launch_bounds__(1024) void k_topk(const unsigned long long* __restrict__ keys,
                                               const float* __restrict__ out,
                                               float* __restrict__ bsort,
                                               unsigned char* __restrict__ vflag) {
    __shared__ union U {
        struct { unsigned int hist[8192]; unsigned int gs[256]; } sel;
        unsigned long long arr[6016];
    } sm;
    __shared__ unsigned long long s_pref, s_kth;
    __shared__ unsigned int s_rem, s_G, s_cnt;
    const int n = blockIdx.x, t = threadIdx.x;
    if (t == 0) { s_rem = NPRE; s_pref = 0ull; }
    __syncthreads();
    const int shifts[5] = {51, 38, 25, 12, 0};
    const int widths[5] = {13, 13, 13, 13, 12};
    int plen = 0;
    for (int lev = 0; lev < 5; ++lev) {
        const int nb = 1 << widths[lev];
        const int gsz = nb >> 8;
        for (int b = t; b < nb; b += 1024) sm.sel.hist[b] = 0;
        __syncthreads();
        const unsigned long long pref = s_pref;
        for (int i = t; i < NA; i += 1024) {
            unsigned long long key = keys[(size_t)n * NA + i];
            if (plen == 0 || (key >> (64 - plen)) == pref) {
                unsigned int bin = (unsigned int)((key >> shifts[lev]) & (unsigned)(nb - 1));
                atomicAdd(&sm.sel.hist[bin], 1u);
            }
        }
        __syncthreads();
        if (t < 256) {
            unsigned int s = 0;
            for (int m = 0; m < gsz; m++) s += sm.sel.hist[t * gsz + m];
            sm.sel.gs[t] = s;
        }
        __syncthreads();
        for (int off = 1; off < 256; off <<= 1) {
            unsigned int v = 0;
            if (t < 256 && t + off < 256) v = sm.sel.gs[t + off];
            __syncthreads();
            if (t < 256) sm.sel.gs[t] += v;
            __syncthreads();
        }
        const unsigned int rem = s_rem;
        if (t < 256) {
            unsigned int here = sm.sel.gs[t];
            unsigned int above = (t == 255) ? 0u : sm.sel.gs[t + 1];
            if (here >= rem && above < rem) s_G = (unsigned int)t;
        }
        __syncthreads();
        if (t == 0) {
            int G = (int)s_G;
            unsigned int acc = (G == 255) ? 0u : sm.sel.gs[G + 1];
            int selbin = G * gsz;
            for (int b = G * gsz + gsz - 1; b >= G * gsz; --b) {
                if (acc + sm.sel.hist[b] >= rem) { selbin = b; break; }
                acc += sm.sel.hist[b];
            }
            s_rem = rem - acc;
            s_pref = (s_pref << widths[lev]) | (unsigned long long)(unsigned)selbin;
        }
        plen += widths[lev];
        __syncthreads();
    }
    if (t == 0) { s_kth = s_pref; s_cnt = 0u; }
    __syncthreads();
    const unsigned long long kth = s_kth;
    // compact: exactly NPRE keys >= kth into LDS (overlays hist - select done)
    for (int i = t; i < NA; i += 1024) {
        unsigned long long key = keys[(size_t)n * NA + i];
        if (key >= kth) {
            unsigned int p = atomicAdd(&s_cnt, 1u);
            if (p < 6016) sm.arr[p] = key;
        }
    }
    __syncthreads();
    // rank-by-count: thread t owns keys at t, t+1024, ... (up to 6)
    unsigned long long myk[6];
    int myr[6];
#pragma unroll
    for (int m = 0; m < 6; ++m) {
        int idx = t + m * 1024;
        myk[m] = (idx < NPRE) ? sm.arr[idx] : 0xFFFFFFFFFFFFFFFFull;
        myr[m] = 0;
    }
#pragma unroll 4
    for (int j = 0; j < NPRE; ++j) {
        unsigned long long kj = sm.arr[j];
#pragma unroll
        for (int m = 0; m < 6; ++m) myr[m] += (kj > myk[m]) ? 1 : 0;
    }
#pragma unroll
    for (int m = 0; m < 6; ++m) {
        int idx = t + m * 1024;
        if (idx >= NPRE) continue;
        unsigned long long key = myk[m];
        unsigned int i = 0xFFFFu - (unsigned int)(key & 0xFFFFull);
        int pos = i / 9, a = i - pos * 9;
        float anc[4]; anchor_for(a, pos, anc);
        float4 L = *(const float4*)&out[O_LOCS + (size_t)(n * NA + i) * 4];
        float box[4];
        bool ok = decode_box(L, anc, box);
        ((float4*)bsort)[(size_t)n * NPRE + myr[m]] =
            make_float4(box[0], box[1], box[2], box[3]);
        vflag[(size_t)n * NPRE + myr[m]] = ok ? 1 : 0;
    }
}

// ---------------- suppression bitmask matrix (bits j>i with IoU>0.7) -----------------
__global__ __launch_bounds__(256) void k_mask(const float* __restrict__ bsort,
                                              unsigned long long* __restrict__ masks) {
    __shared__ float4 bx[1024];
    const int n  = blockIdx.z;
    const int jc = blockIdx.y;
    const int i  = blockIdx.x * 256 + threadIdx.x;
    const bool have = i < NPRE;
    float4 bi = make_float4(0, 0, 0, 0); float areai = 0.f;
    if (have) {
        bi = ((const float4*)bsort)[(size_t)n * NPRE + i];
        areai = fmulr(fsubr(bi.z, bi.x), fsubr(bi.w, bi.y));
    }
    const int jn = min(1024, NPRE - jc * 1024);
    for (int jj = threadIdx.x; jj < jn; jj += 256)
        bx[jj] = ((const float4*)bsort)[(size_t)n * NPRE + jc * 1024 + jj];
    __syncthreads();
    for (int w = 0; w < 16; ++w) {
        int gw = jc * 16 + w;
        if (gw >= NWORD) break;
        unsigned long long m = 0ull;
        int jbase = jc * 1024 + w * 64;
        if (have && jbase + 63 > i) {
#pragma unroll 1
            for (int b = 0; b < 64; b++) {
                int j = jbase + b;
                if (j > i && j < NPRE) {
                    float4 bj = bx[w * 64 + b];
                    float ih = fmaxf(fsubr(fminf(bi.z, bj.z), fmaxf(bi.x, bj.x)), 0.f);
                    float iw = fmaxf(fsubr(fminf(bi.w, bj.w), fmaxf(bi.y, bj.y)), 0.f);
                    float inter = fmulr(ih, iw);
                    float areaj = fmulr(fsubr(bj.z, bj.x), fsubr(bj.w, bj.y));
                    float den = faddr(fsubr(faddr(areai, areaj), inter), 1e-9f);
                    float iou = __fdiv_rn(inter, den);
                    if (iou > 0.7f) m |= (1ull << b);
                }
            }
        }
        if (have) masks[((size_t)n * NPRE + i) * NWORD + gw] = m;
    }
}

// ---------------- greedy NMS scan: 1 wave/image, register bitmaps, skip-scan ---------
__global__ __launch_bounds__(64) void k_scan(const unsigned long long* __restrict__ masks,
                                             const unsigned char* __restrict__ vflag,
                                             const float* __restrict__ bsort,
                                             float* __restrict__ out) {
    const int n = blockIdx.x;
    const int l = threadIdx.x;
    unsigned long long valw0 = 0ull, valw1 = 0ull;
    for (int w = 0; w < NWORD; ++w) {
        int idx = w * 64 + l;
        bool v = (idx < NPRE) && (vflag[(size_t)n * NPRE + idx] != 0);
        unsigned long long word = __ballot(v);
        if (w == l) valw0 = word;
        if (w == 64 + l) valw1 = word;
    }
    unsigned long long sup0 = 0ull, sup1 = 0ull;
    int kept = 0;
    while (kept < NPOST) {
        unsigned long long cand0 = valw0 & ~sup0;
        unsigned long long cand1 = (l < NWORD - 64) ? (valw1 & ~sup1) : 0ull;
        unsigned long long b0 = __ballot(cand0 != 0ull);
        int w; unsigned long long bits;
        if (b0) {
            int fl = __ffsll((long long)b0) - 1;
            w = fl; bits = __shfl(cand0, fl);
        } else {
            unsigned long long b1 = __ballot(cand1 != 0ull);
            if (!b1) break;
            int fl = __ffsll((long long)b1) - 1;
            w = 64 + fl; bits = __shfl(cand1, fl);
        }
        int i = w * 64 + (__ffsll((long long)bits) - 1);
        if (l == 0) {
            float4 b4 = ((const float4*)bsort)[(size_t)n * NPRE + i];
            out[O_ROIS + (size_t)(n * NPOST + kept) * 4 + 0] = b4.x;
            out[O_ROIS + (size_t)(n * NPOST + kept) * 4 + 1] = b4.y;
            out[O_ROIS + (size_t)(n * NPOST + kept) * 4 + 2] = b4.z;
            out[O_ROIS + (size_t)(n * NPOST + kept) * 4 + 3] = b4.w;
            out[O_RIDX + n * NPOST + kept] = (float)n;
        }
        kept++;
        if (kept >= NPOST) break;
        const unsigned long long* mrow = masks + ((size_t)n * NPRE + i) * NWORD;
        sup0 |= mrow[l];
        if (l < NWORD - 64) sup1 |= mrow[64 + l];
        if (w < 64) { if (l == w) sup0 |= (1ull << (i & 63)); }
        else        { if (l == w - 64) sup1 |= (1ull << (i & 63)); }
    }
    for (int r = kept + l; r < NPOST; r += 64) {
        out[O_ROIS + (size_t)(n * NPOST + r) * 4 + 0] = 0.f;
        out[O_ROIS + (size_t)(n * NPOST + r) * 4 + 1] = 0.f;
        out[O_ROIS + (size_t)(n * NPOST + r) * 4 + 2] = 0.f;
        out[O_ROIS + (size_t)(n * NPOST + r) * 4 + 3] = 0.f;
        out[O_RIDX + n * NPOST + r] = -1.0f;
    }
}

extern "C" void kernel_launch(void* const* d_in, const int* in_sizes, int n_in,
                              void* d_out, int out_size, void* d_ws, size_t ws_size,
                              hipStream_t stream) {
    const float* x   = (const float*)d_in[0];
    const float* w1  = (const float*)d_in[1];
    const float* b1  = (const float*)d_in[2];
    const float* wsc = (const float*)d_in[3];
    const float* bsc = (const float*)d_in[4];
    const float* wlc = (const float*)d_in[5];
    const float* blc = (const float*)d_in[6];
    float* out = (float*)d_out;
    char* ws = (char*)d_ws;

    float* wr2                = (float*)(ws + 0);                       //  9,437,184
    float* mid                = (float*)(ws + 9437184);                 // 67,108,864
    double* fgbuf             = (double*)(ws + 76546048);               //  2,359,296
    unsigned long long* keys  = (unsigned long long*)(ws + 78905344);   //  2,359,296
    float* bsort              = (float*)(ws + 81789952);                //    768,000
    unsigned char* vflag      = (unsigned char*)(ws + 82557952);        //     48,128
    unsigned long long* masks = (unsigned long long*)(ws + 82606080);   // 36,096,000

    dim3 gw(128, 8);
    k_wreord<<<gw, 256, 0, stream>>>(w1, wr2);
    dim3 g3(16, 8, 8);
    k_conv3<<<g3, 256, 0, stream>>>(x, wr2, b1, mid);
    dim3 g1(64, 8);
    k_conv1<<<g1, 256, 0, stream>>>(mid, wlc, blc, wsc, bsc, out, fgbuf);
    k_keys<<<1152, 256, 0, stream>>>(out, fgbuf, keys, out);
    k_topk<<<8, 1024, 0, stream>>>(keys, out, bsort, vflag);
    dim3 gm(24, 6, 8);
    k_mask<<<gm, 256, 0, stream>>>(bsort, masks);
    k_scan<<<8, 64, 0, stream>>>(masks, vflag, bsort, out);
}

// Round 15
// 2587.705 us; speedup vs baseline: 1.4622x; 1.4622x over previous
//
#include <hip/hip_runtime.h>
#include <cstdint>
#include <cstddef>

#define CIN 512
#define NA 36864           // 4096 positions * 9 anchors
#define NPRE 6000
#define NPOST 300
#define NWORD 94           // ceil(6000/64)
#define NEGV -1000000000.0f
#define ISTRIDE 76         // input LDS row stride (19 quads, odd -> bank spread)

// d_out float offsets (return-order concat)
#define O_LOCS   0
#define O_SCORES 1179648   // 8*36864*4
#define O_ROIS   1769472   // + 8*36864*2
#define O_RIDX   1779072   // + 8*300*4
#define O_ANCH   1781472   // + 8*300

// ---------- exact-rounding helpers (ordering-critical code only) --------------------
__device__ __forceinline__ float fmulr(float a, float b) { return __fmul_rn(a, b); }
__device__ __forceinline__ float faddr(float a, float b) { return __fadd_rn(a, b); }
__device__ __forceinline__ float fsubr(float a, float b) { return __fsub_rn(a, b); }

__device__ __forceinline__ void anchor_for(int a, int pos, float* anc) {
    const double rat[3] = {0.5, 1.0, 2.0};
    const double scl[3] = {8.0, 16.0, 32.0};
    int ri = a / 3, si = a - ri * 3;
    double h = 16.0 * scl[si] * sqrt(rat[ri]);
    double w = 16.0 * scl[si] * sqrt(1.0 / rat[ri]);
    float a0 = (float)(8.0 - h * 0.5);
    float a1 = (float)(8.0 - w * 0.5);
    float a2 = (float)(8.0 + h * 0.5);
    float a3 = (float)(8.0 + w * 0.5);
    int y = pos >> 6, x = pos & 63;
    float sy = (float)(y * 16), sx = (float)(x * 16);
    anc[0] = faddr(a0, sy); anc[1] = faddr(a1, sx);
    anc[2] = faddr(a2, sy); anc[3] = faddr(a3, sx);
}

__device__ __forceinline__ bool decode_box(float4 L, const float* anc, float* box) {
    float ah  = fsubr(anc[2], anc[0]);
    float aw  = fsubr(anc[3], anc[1]);
    float acy = faddr(anc[0], fmulr(0.5f, ah));
    float acx = faddr(anc[1], fmulr(0.5f, aw));
    float cy  = faddr(fmulr(L.x, ah), acy);
    float cx  = faddr(fmulr(L.y, aw), acx);
    float h   = fmulr(ah, expf(L.z));
    float w   = fmulr(aw, expf(L.w));
    float y1 = fminf(fmaxf(fsubr(cy, fmulr(0.5f, h)), 0.0f), 1024.0f);
    float x1 = fminf(fmaxf(fsubr(cx, fmulr(0.5f, w)), 0.0f), 1024.0f);
    float y2 = fminf(fmaxf(faddr(cy, fmulr(0.5f, h)), 0.0f), 1024.0f);
    float x2 = fminf(fmaxf(faddr(cx, fmulr(0.5f, w)), 0.0f), 1024.0f);
    box[0] = y1; box[1] = x1; box[2] = y2; box[3] = x2;
    float hs = fsubr(y2, y1), ws2 = fsubr(x2, x1);
    return (hs >= 16.0f) && (ws2 >= 16.0f);
}

// monotonic 64-bit map of a double (totally ordered, sign handled)
__device__ __forceinline__ unsigned long long mono64(double f) {
    unsigned long long u = (unsigned long long)__double_as_longlong(f);
    return (u & 0x8000000000000000ull) ? ~u : (u | 0x8000000000000000ull);
}

// ---------------- weight reorder: w1[oc][c][ky][kx] -> wr2[ocb64][ct(c*9+tap)][o64] --
__global__ __launch_bounds__(256) void k_wreord(const float* __restrict__ w1,
                                                float* __restrict__ wr2) {
    __shared__ float tile[64][37];
    const int ct0 = blockIdx.x * 36;   // 128 chunks over 4608
    const int ocb = blockIdx.y;        // 8
    const int t = threadIdx.x;
    for (int i = t; i < 64 * 36; i += 256) {
        int orow = i / 36, c = i - orow * 36;
        tile[orow][c] = w1[(size_t)(ocb * 64 + orow) * 4608 + ct0 + c];
    }
    __syncthreads();
    for (int i = t; i < 36 * 64; i += 256) {
        int ct = i >> 6, o = i & 63;
        wr2[((size_t)ocb * 4608 + ct0 + ct) * 64 + o] = tile[o][ct];
    }
}

// ---------------- 3x3 conv 512->512 + bias + relu, pure fp32 (R13 verbatim) ----------
// Best measured conv3 (1975-2029 us). Per-thread 4 oc x 2 rows x 8 cols
// (block 64oc x 4row x 64col); LDS reads 21 b128/cc for 576 FMA -> FMA-bound.
// launch_bounds(256,2): acc+sub=128 regs NEED the full 256-VGPR budget — capping
// at 3 waves/SIMD (R14) spilled to scratch (WRITE 65MB->3.6GB, +30% time).
// Summation tree per OUTPUT ELEMENT identical to rounds 5-13 (8-ch fp32 sub-chunk,
// cc->dy->dx order, fp32 merge into acc) -> bit-identical mid.
__global__ __launch_bounds__(256, 2) void k_conv3(const float* __restrict__ x,
                                                  const float* __restrict__ wr2,
                                                  const float* __restrict__ b1,
                                                  float* __restrict__ mid) {
    __shared__ float in_s[8 * 6 * ISTRIDE];   // 3648 floats
    __shared__ float w_s[8 * 9 * 64];         // 4608 floats
    const int yb  = blockIdx.x;          // 16
    const int ocb = blockIdx.y;          // 8
    const int n   = blockIdx.z;          // 8
    const int t   = threadIdx.x;
    const int y0  = yb * 4;
    const int cg  = t & 7;               // col group: cols cg*8..cg*8+7
    const int rg  = (t >> 3) & 1;        // row pair: rows rg*2, rg*2+1
    const int ocg = t >> 4;              // 0..15 -> ocs ocg*4..ocg*4+3
    const int xo  = cg << 3;

    // zero halo words (gx=-1 at word 4, gx=64 at word 69) on all 48 rows, once
    if (t < 48) { in_s[t * ISTRIDE + 4] = 0.f; in_s[t * ISTRIDE + 69] = 0.f; }

    // staging: 768 f4 slots (48 rows x 16), 3 per thread; LDS dest word 5+4c is only
    // 4B-aligned -> 4 scalar b32 writes per slot (writes are rare; reads stay b128).
    int   ilds[3];
    int   ival[3];
    const float* igp[3];
#pragma unroll
    for (int k = 0; k < 3; ++k) {
        int s = t + k * 256;
        int row = s >> 4, c = s & 15;
        int cc = row / 6, rr = row - cc * 6;
        int gy = y0 - 1 + rr;
        ival[k] = (gy >= 0 && gy < 64) ? 1 : 0;
        int gyc = min(max(gy, 0), 63);
        ilds[k] = row * ISTRIDE + 5 + c * 4;
        igp[k]  = x + (((size_t)(n * CIN + cc) * 64 + gyc) * 64 + c * 4);
    }
    const float* wgp = wr2 + (size_t)ocb * (4608 * 64);

    float acc[4][2][8];
#pragma unroll
    for (int o = 0; o < 4; o++)
#pragma unroll
        for (int rr = 0; rr < 2; rr++)
#pragma unroll
            for (int j = 0; j < 8; j++) acc[o][rr][j] = 0.f;

    for (int ch = 0; ch < 64; ++ch) {
        // ---- stage weights: linear float4 copy of 4608 floats ----
        const float* wp0 = wgp + (size_t)ch * 4608;
#pragma unroll
        for (int k = 0; k < 4; ++k)
            *(float4*)&w_s[4 * t + 1024 * k] = *(const float4*)(wp0 + 4 * t + 1024 * k);
        if (t < 128)
            *(float4*)&w_s[4 * t + 4096] = *(const float4*)(wp0 + 4 * t + 4096);
        // ---- stage input: 3 slots per thread (aligned global f4 -> 4 b32 LDS) ----
#pragma unroll
        for (int k = 0; k < 3; ++k) {
            float4 v = make_float4(0.f, 0.f, 0.f, 0.f);
            if (ival[k]) v = *(const float4*)(igp[k] + (size_t)ch * 32768);
            in_s[ilds[k] + 0] = v.x;
            in_s[ilds[k] + 1] = v.y;
            in_s[ilds[k] + 2] = v.z;
            in_s[ilds[k] + 3] = v.w;
        }
        __syncthreads();

        float sub[4][2][8];
#pragma unroll
        for (int o = 0; o < 4; o++)
#pragma unroll
            for (int rr = 0; rr < 2; rr++)
#pragma unroll
                for (int j = 0; j < 8; j++) sub[o][rr][j] = 0.f;
#pragma unroll 1
        for (int cc = 0; cc < 8; ++cc) {
            // load the 4 input rows this thread needs (window gx xo-1 .. xo+10)
            float in4r[4][12];
#pragma unroll
            for (int k = 0; k < 4; ++k) {
                const float4* ip = (const float4*)
                    &in_s[cc * (6 * ISTRIDE) + (rg * 2 + k) * ISTRIDE + xo + 4];
                float4 A = ip[0], B = ip[1], C4 = ip[2];
                in4r[k][0] = A.x;  in4r[k][1] = A.y;  in4r[k][2]  = A.z;  in4r[k][3]  = A.w;
                in4r[k][4] = B.x;  in4r[k][5] = B.y;  in4r[k][6]  = B.z;  in4r[k][7]  = B.w;
                in4r[k][8] = C4.x; in4r[k][9] = C4.y; in4r[k][10] = C4.z; in4r[k][11] = C4.w;
            }
#pragma unroll
            for (int dy = 0; dy < 3; ++dy) {
#pragma unroll
                for (int dx = 0; dx < 3; ++dx) {
                    const float4* wp =
                        (const float4*)&w_s[cc * 576 + (dy * 3 + dx) * 64 + ocg * 4];
                    float4 W = wp[0];
                    float w4[4] = {W.x, W.y, W.z, W.w};
#pragma unroll
                    for (int o = 0; o < 4; ++o)
#pragma unroll
                        for (int rr = 0; rr < 2; ++rr)
#pragma unroll
                            for (int j = 0; j < 8; ++j)
                                sub[o][rr][j] += w4[o] * in4r[rr + dy][j + dx];
                }
            }
        }
#pragma unroll
        for (int o = 0; o < 4; o++)
#pragma unroll
            for (int rr = 0; rr < 2; rr++)
#pragma unroll
                for (int j = 0; j < 8; j++) acc[o][rr][j] += sub[o][rr][j];
        __syncthreads();
    }
    const int ocbase = (ocb << 6) + ocg * 4;
#pragma unroll
    for (int o = 0; o < 4; o++) {
        float bb = b1[ocbase + o];
#pragma unroll
        for (int rr = 0; rr < 2; rr++) {
            const int gy = y0 + rg * 2 + rr;
            float4 v0, v1;
            v0.x = fmaxf(acc[o][rr][0] + bb, 0.f);
            v0.y = fmaxf(acc[o][rr][1] + bb, 0.f);
            v0.z = fmaxf(acc[o][rr][2] + bb, 0.f);
            v0.w = fmaxf(acc[o][rr][3] + bb, 0.f);
            v1.x = fmaxf(acc[o][rr][4] + bb, 0.f);
            v1.y = fmaxf(acc[o][rr][5] + bb, 0.f);
            v1.z = fmaxf(acc[o][rr][6] + bb, 0.f);
            v1.w = fmaxf(acc[o][rr][7] + bb, 0.f);
            float* mp = &mid[((size_t)(n * CIN + ocbase + o) * 64 + gy) * 64 + xo];
            *(float4*)(mp + 0) = v0;
            *(float4*)(mp + 4) = v1;
        }
    }
}

// ---------------- fused 1x1 convs (36 loc + 18 score), f64 accumulation --------------
__global__ __launch_bounds__(256) void k_conv1(const float* __restrict__ mid,
                                               const float* __restrict__ wl,
                                               const float* __restrict__ bl,
                                               const float* __restrict__ wsc,
                                               const float* __restrict__ bs,
                                               float* __restrict__ out,
                                               double* __restrict__ fgbuf) {
    __shared__ float in_s[128 * 64];
    __shared__ float w_s[128 * 64];   // [cc][og*16+k], invalid slots zero
    const int y = blockIdx.x;   // 64
    const int n = blockIdx.y;   // 8
    const int t = threadIdx.x;
    const int xx = t & 63, og = t >> 6;   // og uniform per wave
    double accd[14];
#pragma unroll
    for (int k = 0; k < 14; k++) accd[k] = 0.0;

    for (int c0 = 0; c0 < 512; c0 += 128) {
        for (int idx = t; idx < 128 * 64; idx += 256) {
            int cc = idx >> 6, x2 = idx & 63;
            in_s[idx] = mid[((n * CIN + c0 + cc) * 64 + y) * 64 + x2];
        }
        for (int idx = t; idx < 128 * 64; idx += 256) {
            int cc = idx >> 6, s = idx & 63;
            int og2 = s >> 4, kk = s & 15;
            int oc = og2 * 14 + kk;
            float v = 0.f;
            if (kk < 14 && oc < 54)
                v = (oc < 36) ? wl[oc * 512 + c0 + cc] : wsc[(oc - 36) * 512 + c0 + cc];
            w_s[cc * 64 + s] = v;
        }
        __syncthreads();
#pragma unroll 1
        for (int cc = 0; cc < 128; ++cc) {
            double iv = (double)in_s[cc * 64 + xx];
            const float4* wq = (const float4*)&w_s[cc * 64 + og * 16];
            float4 W0 = wq[0], W1 = wq[1], W2 = wq[2], W3 = wq[3];
            float wf[16] = {W0.x, W0.y, W0.z, W0.w, W1.x, W1.y, W1.z, W1.w,
                            W2.x, W2.y, W2.z, W2.w, W3.x, W3.y, W3.z, W3.w};
#pragma unroll
            for (int k = 0; k < 14; k++)
                accd[k] += (double)wf[k] * iv;
        }
        __syncthreads();
    }
    const int pos = y * 64 + xx;
    double sv[14];
#pragma unroll
    for (int k = 0; k < 14; k++) {
        int oc = og * 14 + k;
        if (oc >= 54) break;
        if (oc < 36) {
            double v = accd[k] + (double)bl[oc];
            int a = oc >> 2, cd = oc & 3;
            out[O_LOCS + ((size_t)(n * NA + pos * 9 + a)) * 4 + cd] = (float)v;
        } else {
            sv[k] = accd[k] + (double)bs[oc - 36];
            int c2 = oc - 36, a = c2 >> 1, cls = c2 & 1;
            out[O_SCORES + ((size_t)(n * NA + pos * 9 + a)) * 2 + cls] = (float)sv[k];
        }
    }
#pragma unroll
    for (int k = 0; k < 13; k++) {
        int oc = og * 14 + k;
        if (oc >= 36 && oc < 54 && ((oc - 36) & 1) == 0) {
            double s0 = sv[k], s1 = sv[k + 1];
            double m = fmax(s0, s1);
            double e0 = exp(s0 - m), e1 = exp(s1 - m);
            double fg = e1 / (e0 + e1);
            int a = (oc - 36) >> 1;
            fgbuf[(size_t)n * NA + pos * 9 + a] = fg;
        }
    }
}

// ---------------- keys: mono64(f64 fg) low 16 bits = inverted index; + anchors -------
__global__ __launch_bounds__(256) void k_keys(const float* __restrict__ out_ro,
                                              const double* __restrict__ fgbuf,
                                              unsigned long long* __restrict__ keys,
                                              float* __restrict__ out) {
    const int n = blockIdx.x / 144;
    const int i = (blockIdx.x % 144) * 256 + threadIdx.x;
    int pos = i / 9, a = i - pos * 9;
    float anc[4]; anchor_for(a, pos, anc);
    float4 L = *(const float4*)&out_ro[O_LOCS + (size_t)(n * NA + i) * 4];
    float box[4];
    bool ok = decode_box(L, anc, box);
    double f = ok ? fgbuf[(size_t)n * NA + i] : (double)NEGV;
    unsigned long long m = mono64(f);
    keys[(size_t)n * NA + i] =
        (m & 0xFFFFFFFFFFFF0000ull) | (unsigned long long)(0xFFFFu - (unsigned)i);
    if (blockIdx.x < 144) {   // n == 0: also emit anchors output
        out[O_ANCH + (size_t)i * 4 + 0] = anc[0];
        out[O_ANCH + (size_t)i * 4 + 1] = anc[1];
        out[O_ANCH + (size_t)i * 4 + 2] = anc[2];
        out[O_ANCH + (size_t)i * 4 + 3] = anc[3];
    }
}

// ---------------- exact 64-bit radix select: kth[n] = 6000th largest key -------------
__global__ __launch_bounds__(1024) void k_select(const unsigned long long* __restrict__ keys,
                                                 unsigned long long* __restrict__ kth,
                                                 unsigned int* __restrict__ cnt) {
    __shared__ unsigned int hist[8192];
    __shared__ unsigned int gs[256];
    __shared__ unsigned int s_rem, s_G;
    __shared__ unsigned long long s_pref;
    const int n = blockIdx.x, t = threadIdx.x;
    if (t == 0) { s_rem = NPRE; s_pref = 0ull; }
    __syncthreads();
    const int shifts[5] = {51, 38, 25, 12, 0};
    const int widths[5] = {13, 13, 13, 13, 12};
    int plen = 0;
    for (int lev = 0; lev < 5; ++lev) {
        const int nb = 1 << widths[lev];
        const int gsz = nb >> 8;
        for (int b = t; b < nb; b += 1024) hist[b] = 0;
        __syncthreads();
        const unsigned long long pref = s_pref;
        for (int i = t; i < NA; i += 1024) {
            unsigned long long key = keys[(size_t)n * NA + i];
            if (plen == 0 || (key >> (64 - plen)) == pref) {
                unsigned int bin = (unsigned int)((key >> shifts[lev]) & (unsigned)(nb - 1));
                atomicAdd(&hist[bin], 1u);
            }
        }
        __syncthreads();
        if (t < 256) {
            unsigned int s = 0;
            for (int m = 0; m < gsz; m++) s += hist[t * gsz + m];
            gs[t] = s;
        }
        __syncthreads();
        for (int off = 1; off < 256; off <<= 1) {
            unsigned int v = 0;
            if (t < 256 && t + off < 256) v = gs[t + off];
            __syncthreads();
            if (t < 256) gs[t] += v;
            __syncthreads();
        }
        const unsigned int rem = s_rem;
        if (t < 256) {
            unsigned int here = gs[t];
            unsigned int above = (t == 255) ? 0u : gs[t + 1];
            if (here >= rem && above < rem) s_G = (unsigned int)t;
        }
        __syncthreads();
        if (t == 0) {
            int G = (int)s_G;
            unsigned int acc = (G == 255) ? 0u : gs[G + 1];
            int selbin = G * gsz;
            for (int b = G * gsz + gsz - 1; b >= G * gsz; --b) {
                if (acc + hist[b] >= rem) { selbin = b; break; }
                acc += hist[b];
            }
            s_rem = rem - acc;
            s_pref = (s_pref << widths[lev]) | (unsigned long long)(unsigned)selbin;
        }
        plen += widths[lev];
        __syncthreads();
    }
    if (t == 0) { kth[n] = s_pref; cnt[n] = 0u; }
}

// ---------------- compact: exactly the 6000 keys >= kth ------------------------------
__global__ void k_compact(const unsigned long long* __restrict__ keys,
                          const unsigned long long* __restrict__ kth,
                          unsigned long long* __restrict__ cbuf,
                          unsigned int* __restrict__ cnt) {
    const int n = blockIdx.x / 144;
    const int i = (blockIdx.x % 144) * 256 + threadIdx.x;
    unsigned long long key = keys[(size_t)n * NA + i];
    if (key >= kth[n]) {
        unsigned int p = atomicAdd(&cnt[n], 1u);
        if (p < 8192) cbuf[(size_t)n * 8192 + p] = key;
    }
}

// ---------------- rank-by-count: rank = #{keys > mine}; scatter boxes to rank --------
// grid (12 chunks of 512, 8 images). Replaces the 91-phase bitonic sort.
__global__ __launch_bounds__(256) void k_rank(const unsigned long long* __restrict__ cbuf,
                                              const float* __restrict__ out,
                                              float* __restrict__ bsort,
                                              unsigned char* __restrict__ vflag) {
    __shared__ unsigned long long tile[2048];
    const int n = blockIdx.y, t = threadIdx.x;
    const int base = blockIdx.x * 512;
    unsigned long long mykey[2]; int myrank[2]; bool have[2];
#pragma unroll
    for (int m = 0; m < 2; ++m) {
        int idx = base + t * 2 + m;
        have[m] = idx < NPRE;
        mykey[m] = have[m] ? cbuf[(size_t)n * 8192 + idx] : 0ull;
        myrank[m] = 0;
    }
    for (int tb = 0; tb < 3; ++tb) {
        for (int jj = t; jj < 2048; jj += 256) {
            int j = tb * 2048 + jj;
            tile[jj] = (j < NPRE) ? cbuf[(size_t)n * 8192 + j] : 0ull;
        }
        __syncthreads();
        const int jmax = min(2048, NPRE - tb * 2048);
        for (int j = 0; j < jmax; ++j) {
            unsigned long long kj = tile[j];
            if (kj > mykey[0]) myrank[0]++;
            if (kj > mykey[1]) myrank[1]++;
        }
        __syncthreads();
    }
#pragma unroll
    for (int m = 0; m < 2; ++m) {
        if (!have[m]) continue;
        unsigned long long key = mykey[m];
        unsigned int i = 0xFFFFu - (unsigned int)(key & 0xFFFFull);
        int pos = i / 9, a = i - pos * 9;
        float anc[4]; anchor_for(a, pos, anc);
        float4 L = *(const float4*)&out[O_LOCS + (size_t)(n * NA + i) * 4];
        float box[4];
        bool ok = decode_box(L, anc, box);
        ((float4*)bsort)[(size_t)n * NPRE + myrank[m]] =
            make_float4(box[0], box[1], box[2], box[3]);
        vflag[(size_t)n * NPRE + myrank[m]] = ok ? 1 : 0;
    }
}

// ---------------- suppression bitmask matrix (bits j>i with IoU>0.7) -----------------
__global__ __launch_bounds__(256) void k_mask(const float* __restrict__ bsort,
                                              unsigned long long* __restrict__ masks) {
    __shared__ float4 bx[1024];
    const int n  = blockIdx.z;
    const int jc = blockIdx.y;
    const int i  = blockIdx.x * 256 + threadIdx.x;
    const bool have = i < NPRE;
    float4 bi = make_float4(0, 0, 0, 0); float areai = 0.f;
    if (have) {
        bi = ((const float4*)bsort)[(size_t)n * NPRE + i];
        areai = fmulr(fsubr(bi.z, bi.x), fsubr(bi.w, bi.y));
    }
    const int jn = min(1024, NPRE - jc * 1024);
    for (int jj = threadIdx.x; jj < jn; jj += 256)
        bx[jj] = ((const float4*)bsort)[(size_t)n * NPRE + jc * 1024 + jj];
    __syncthreads();
    for (int w = 0; w < 16; ++w) {
        int gw = jc * 16 + w;
        if (gw >= NWORD) break;
        unsigned long long m = 0ull;
        int jbase = jc * 1024 + w * 64;
        if (have && jbase + 63 > i) {
#pragma unroll 1
            for (int b = 0; b < 64; b++) {
                int j = jbase + b;
                if (j > i && j < NPRE) {
                    float4 bj = bx[w * 64 + b];
                    float ih = fmaxf(fsubr(fminf(bi.z, bj.z), fmaxf(bi.x, bj.x)), 0.f);
                    float iw = fmaxf(fsubr(fminf(bi.w, bj.w), fmaxf(bi.y, bj.y)), 0.f);
                    float inter = fmulr(ih, iw);
                    float areaj = fmulr(fsubr(bj.z, bj.x), fsubr(bj.w, bj.y));
                    float den = faddr(fsubr(faddr(areai, areaj), inter), 1e-9f);
                    float iou = __fdiv_rn(inter, den);
                    if (iou > 0.7f) m |= (1ull << b);
                }
            }
        }
        if (have) masks[((size_t)n * NPRE + i) * NWORD + gw] = m;
    }
}

// ---------------- greedy NMS scan: 1 wave/image, register bitmaps, skip-scan ---------
__global__ __launch_bounds__(64) void k_scan(const unsigned long long* __restrict__ masks,
                                             const unsigned char* __restrict__ vflag,
                                             const float* __restrict__ bsort,
                                             float* __restrict__ out) {
    const int n = blockIdx.x;
    const int l = threadIdx.x;
    unsigned long long valw0 = 0ull, valw1 = 0ull;
    for (int w = 0; w < NWORD; ++w) {
        int idx = w * 64 + l;
        bool v = (idx < NPRE) && (vflag[(size_t)n * NPRE + idx] != 0);
        unsigned long long word = __ballot(v);
        if (w == l) valw0 = word;
        if (w == 64 + l) valw1 = word;
    }
    unsigned long long sup0 = 0ull, sup1 = 0ull;
    int kept = 0;
    while (kept < NPOST) {
        unsigned long long cand0 = valw0 & ~sup0;
        unsigned long long cand1 = (l < NWORD - 64) ? (valw1 & ~sup1) : 0ull;
        unsigned long long b0 = __ballot(cand0 != 0ull);
        int w; unsigned long long bits;
        if (b0) {
            int fl = __ffsll((long long)b0) - 1;
            w = fl; bits = __shfl(cand0, fl);
        } else {
            unsigned long long b1 = __ballot(cand1 != 0ull);
            if (!b1) break;
            int fl = __ffsll((long long)b1) - 1;
            w = 64 + fl; bits = __shfl(cand1, fl);
        }
        int i = w * 64 + (__ffsll((long long)bits) - 1);
        if (l == 0) {
            float4 b4 = ((const float4*)bsort)[(size_t)n * NPRE + i];
            out[O_ROIS + (size_t)(n * NPOST + kept) * 4 + 0] = b4.x;
            out[O_ROIS + (size_t)(n * NPOST + kept) * 4 + 1] = b4.y;
            out[O_ROIS + (size_t)(n * NPOST + kept) * 4 + 2] = b4.z;
            out[O_ROIS + (size_t)(n * NPOST + kept) * 4 + 3] = b4.w;
            out[O_RIDX + n * NPOST + kept] = (float)n;
        }
        kept++;
        if (kept >= NPOST) break;
        const unsigned long long* mrow = masks + ((size_t)n * NPRE + i) * NWORD;
        sup0 |= mrow[l];
        if (l < NWORD - 64) sup1 |= mrow[64 + l];
        if (w < 64) { if (l == w) sup0 |= (1ull << (i & 63)); }
        else        { if (l == w - 64) sup1 |= (1ull << (i & 63)); }
    }
    for (int r = kept + l; r < NPOST; r += 64) {
        out[O_ROIS + (size_t)(n * NPOST + r) * 4 + 0] = 0.f;
        out[O_ROIS + (size_t)(n * NPOST + r) * 4 + 1] = 0.f;
        out[O_ROIS + (size_t)(n * NPOST + r) * 4 + 2] = 0.f;
        out[O_ROIS + (size_t)(n * NPOST + r) * 4 + 3] = 0.f;
        out[O_RIDX + n * NPOST + r] = -1.0f;
    }
}

extern "C" void kernel_launch(void* const* d_in, const int* in_sizes, int n_in,
                              void* d_out, int out_size, void* d_ws, size_t ws_size,
                              hipStream_t stream) {
    const float* x   = (const float*)d_in[0];
    const float* w1  = (const float*)d_in[1];
    const float* b1  = (const float*)d_in[2];
    const float* wsc = (const float*)d_in[3];
    const float* bsc = (const float*)d_in[4];
    const float* wlc = (const float*)d_in[5];
    const float* blc = (const float*)d_in[6];
    float* out = (float*)d_out;
    char* ws = (char*)d_ws;

    float* wr2                = (float*)(ws + 0);                       //  9,437,184
    float* mid                = (float*)(ws + 9437184);                 // 67,108,864
    double* fgbuf             = (double*)(ws + 76546048);               //  2,359,296
    unsigned long long* keys  = (unsigned long long*)(ws + 78905344);   //  2,359,296
    unsigned long long* kth   = (unsigned long long*)(ws + 81264640);   //        64
    unsigned int* cnt         = (unsigned int*)(ws + 81265152);         //        32
    unsigned long long* cbuf  = (unsigned long long*)(ws + 81265664);   //    524,288
    float* bsort              = (float*)(ws + 81789952);                //    768,000
    unsigned char* vflag      = (unsigned char*)(ws + 82557952);        //     48,128
    unsigned long long* masks = (unsigned long long*)(ws + 82606080);   // 36,096,000

    dim3 gw(128, 8);
    k_wreord<<<gw, 256, 0, stream>>>(w1, wr2);
    dim3 g3(16, 8, 8);
    k_conv3<<<g3, 256, 0, stream>>>(x, wr2, b1, mid);
    dim3 g1(64, 8);
    k_conv1<<<g1, 256, 0, stream>>>(mid, wlc, blc, wsc, bsc, out, fgbuf);
    k_keys<<<1152, 256, 0, stream>>>(out, fgbuf, keys, out);
    k_select<<<8, 1024, 0, stream>>>(keys, kth, cnt);
    k_compact<<<1152, 256, 0, stream>>>(keys, kth, cbuf, cnt);
    dim3 gr(12, 8);
    k_rank<<<gr, 256, 0, stream>>>(cbuf, out, bsort, vflag);
    dim3 gm(24, 6, 8);
    k_mask<<<gm, 256, 0, stream>>>(bsort, masks);
    k_scan<<<8, 64, 0, stream>>>(masks, vflag, bsort, out);
}